// Round 2
// baseline (109.568 us; speedup 1.0000x reference)
//
#include <hip/hip_runtime.h>
#include <math.h>

static constexpr int NPOS = 32 * 56 * 56;   // 100352 spatial positions
static constexpr int CCH  = 256;            // channels
static constexpr double EPSV = 1e-6;

// ---------------------------------------------------------------------------
// Kernel 1: per-d statistics. Lane = d (0..63). Wave loads 4 coalesced 256B
// segments per position. S layout: [14][64] doubles:
// q=0..3 sums(r,i,j,k), q=4..13 products (rr,ri,rj,rk,ii,ij,ik,jj,jk,kk)
// ---------------------------------------------------------------------------
__global__ __launch_bounds__(256) void hbn_reduce(const float* __restrict__ x,
                                                  double* __restrict__ S) {
  const int tid  = threadIdx.x;
  const int lane = tid & 63;
  const int gw   = blockIdx.x * (blockDim.x >> 6) + (tid >> 6);
  const int nw   = gridDim.x * (blockDim.x >> 6);

  float s0=0.f, s1=0.f, s2=0.f, s3=0.f;
  float q0=0.f,q1=0.f,q2=0.f,q3=0.f,q4=0.f,q5=0.f,q6=0.f,q7=0.f,q8=0.f,q9=0.f;

  for (int p = gw * 2; p < NPOS; p += nw * 2) {
    const float* b = x + (size_t)p * CCH + lane;
    float r0 = b[0],   i0 = b[64],  j0 = b[128], k0 = b[192];
    float r1 = b[256], i1 = b[320], j1 = b[384], k1 = b[448];
    s0 += r0 + r1; s1 += i0 + i1; s2 += j0 + j1; s3 += k0 + k1;
    q0 = fmaf(r0,r0, fmaf(r1,r1, q0));
    q1 = fmaf(r0,i0, fmaf(r1,i1, q1));
    q2 = fmaf(r0,j0, fmaf(r1,j1, q2));
    q3 = fmaf(r0,k0, fmaf(r1,k1, q3));
    q4 = fmaf(i0,i0, fmaf(i1,i1, q4));
    q5 = fmaf(i0,j0, fmaf(i1,j1, q5));
    q6 = fmaf(i0,k0, fmaf(i1,k1, q6));
    q7 = fmaf(j0,j0, fmaf(j1,j1, q7));
    q8 = fmaf(j0,k0, fmaf(j1,k1, q8));
    q9 = fmaf(k0,k0, fmaf(k1,k1, q9));
  }

  __shared__ float red[14][256];
  red[0][tid]=s0;  red[1][tid]=s1;  red[2][tid]=s2;  red[3][tid]=s3;
  red[4][tid]=q0;  red[5][tid]=q1;  red[6][tid]=q2;  red[7][tid]=q3;
  red[8][tid]=q4;  red[9][tid]=q5;  red[10][tid]=q6; red[11][tid]=q7;
  red[12][tid]=q8; red[13][tid]=q9;
  __syncthreads();
  if (tid < 64) {
#pragma unroll
    for (int q = 0; q < 14; ++q) {
      double v = (double)red[q][tid] + (double)red[q][tid+64]
               + (double)red[q][tid+128] + (double)red[q][tid+192];
      unsafeAtomicAdd(&S[q*64 + tid], v);   // native global_atomic_add_f64
    }
  }
}

// ---------------------------------------------------------------------------
// Kernel 2: per-d 4x4 covariance (f64 assembly) -> V^{-1/2} via f32 Jacobi
// -> fold with affine G and mean/beta into M[d] (4x4) + per-channel offset.
// 1 block x 64 threads; fully unrolled -> registers.
// ---------------------------------------------------------------------------
__global__ void hbn_solve(const double* __restrict__ S,
                          const float* __restrict__ beta,
                          const float* __restrict__ grr, const float* __restrict__ gri,
                          const float* __restrict__ grj, const float* __restrict__ grk,
                          const float* __restrict__ gii, const float* __restrict__ gij,
                          const float* __restrict__ gik, const float* __restrict__ gjj,
                          const float* __restrict__ gjk, const float* __restrict__ gkk,
                          float* __restrict__ Mmat, float* __restrict__ offv) {
  const int d = threadIdx.x;   // 0..63
  const double invM = 1.0 / (double)NPOS;

  double mu[4];
  mu[0] = S[0*64+d]*invM; mu[1] = S[1*64+d]*invM;
  mu[2] = S[2*64+d]*invM; mu[3] = S[3*64+d]*invM;

  // f32 working copy of the 4x4 covariance (well-conditioned: data ~N(0,1))
  float A[4][4];
  A[0][0] = (float)(S[4*64+d]*invM  - mu[0]*mu[0] + EPSV);
  A[0][1] = A[1][0] = (float)(S[5*64+d]*invM  - mu[0]*mu[1]);
  A[0][2] = A[2][0] = (float)(S[6*64+d]*invM  - mu[0]*mu[2]);
  A[0][3] = A[3][0] = (float)(S[7*64+d]*invM  - mu[0]*mu[3]);
  A[1][1] = (float)(S[8*64+d]*invM  - mu[1]*mu[1] + EPSV);
  A[1][2] = A[2][1] = (float)(S[9*64+d]*invM  - mu[1]*mu[2]);
  A[1][3] = A[3][1] = (float)(S[10*64+d]*invM - mu[1]*mu[3]);
  A[2][2] = (float)(S[11*64+d]*invM - mu[2]*mu[2] + EPSV);
  A[2][3] = A[3][2] = (float)(S[12*64+d]*invM - mu[2]*mu[3]);
  A[3][3] = (float)(S[13*64+d]*invM - mu[3]*mu[3] + EPSV);

  float U[4][4] = {{1,0,0,0},{0,1,0,0},{0,0,1,0},{0,0,0,1}};

#pragma unroll 1
  for (int sweep = 0; sweep < 6; ++sweep) {
#pragma unroll
    for (int p = 0; p < 3; ++p) {
#pragma unroll
      for (int q = p + 1; q < 4; ++q) {
        float apq = A[p][q];
        if (fabsf(apq) > 1e-30f) {
          float theta = (A[q][q] - A[p][p]) / (2.0f * apq);
          float t = 1.0f / (fabsf(theta) + sqrtf(fmaf(theta, theta, 1.0f)));
          if (theta < 0.0f) t = -t;
          float c = rsqrtf(fmaf(t, t, 1.0f));
          float s = t * c;
#pragma unroll
          for (int r = 0; r < 4; ++r) {
            float arp = A[r][p], arq = A[r][q];
            A[r][p] = c*arp - s*arq;  A[r][q] = s*arp + c*arq;
          }
#pragma unroll
          for (int r = 0; r < 4; ++r) {
            float apr = A[p][r], aqr = A[q][r];
            A[p][r] = c*apr - s*aqr;  A[q][r] = s*apr + c*aqr;
          }
#pragma unroll
          for (int r = 0; r < 4; ++r) {
            float urp = U[r][p], urq = U[r][q];
            U[r][p] = c*urp - s*urq;  U[r][q] = s*urp + c*urq;
          }
        }
      }
    }
  }

  float wis[4];
#pragma unroll
  for (int b = 0; b < 4; ++b) {
    float w = A[b][b];
    if (w < 1e-12f) w = 1e-12f;
    wis[b] = rsqrtf(w);
  }

  // Wm = U diag(wis) U^T
  float Wm[4][4];
#pragma unroll
  for (int a = 0; a < 4; ++a)
#pragma unroll
    for (int cc = 0; cc < 4; ++cc) {
      float acc = 0.0f;
#pragma unroll
      for (int b = 0; b < 4; ++b) acc += U[a][b] * wis[b] * U[cc][b];
      Wm[a][cc] = acc;
    }

  float G[4][4];
  G[0][0] = grr[d]; G[0][1] = G[1][0] = gri[d];
  G[0][2] = G[2][0] = grj[d]; G[0][3] = G[3][0] = grk[d];
  G[1][1] = gii[d]; G[1][2] = G[2][1] = gij[d];
  G[1][3] = G[3][1] = gik[d];
  G[2][2] = gjj[d]; G[2][3] = G[3][2] = gjk[d];
  G[3][3] = gkk[d];

  float M[4][4];
#pragma unroll
  for (int e = 0; e < 4; ++e)
#pragma unroll
    for (int cc = 0; cc < 4; ++cc) {
      float acc = 0.0f;
#pragma unroll
      for (int b = 0; b < 4; ++b) acc += G[e][b] * Wm[b][cc];
      M[e][cc] = acc;
      Mmat[d*16 + e*4 + cc] = acc;
    }

  // off[e] = beta - M*mean
#pragma unroll
  for (int e = 0; e < 4; ++e) {
    float acc = beta[e*64 + d];
#pragma unroll
    for (int cc = 0; cc < 4; ++cc) acc -= M[e][cc] * (float)mu[cc];
    offv[e*64 + d] = acc;
  }
}

// ---------------------------------------------------------------------------
// Kernel 3: y = ELU(M[d] * x_rijk + off). Nontemporal stores: out is never
// re-read, and bypassing keeps x resident in L2/L3 for the reads.
// ---------------------------------------------------------------------------
__global__ __launch_bounds__(256) void hbn_apply(const float* __restrict__ x,
                                                 const float* __restrict__ Mmat,
                                                 const float* __restrict__ offv,
                                                 float* __restrict__ out) {
  const int tid  = threadIdx.x;
  const int lane = tid & 63;
  const int gw   = blockIdx.x * (blockDim.x >> 6) + (tid >> 6);
  const int nw   = gridDim.x * (blockDim.x >> 6);

  const float m0  = Mmat[lane*16+0],  m1  = Mmat[lane*16+1],  m2  = Mmat[lane*16+2],  m3  = Mmat[lane*16+3];
  const float m4  = Mmat[lane*16+4],  m5  = Mmat[lane*16+5],  m6  = Mmat[lane*16+6],  m7  = Mmat[lane*16+7];
  const float m8  = Mmat[lane*16+8],  m9  = Mmat[lane*16+9],  m10 = Mmat[lane*16+10], m11 = Mmat[lane*16+11];
  const float m12 = Mmat[lane*16+12], m13 = Mmat[lane*16+13], m14 = Mmat[lane*16+14], m15 = Mmat[lane*16+15];
  const float o0 = offv[lane], o1 = offv[64+lane], o2 = offv[128+lane], o3 = offv[192+lane];

  for (int p = gw * 2; p < NPOS; p += nw * 2) {
    const float* b = x + (size_t)p * CCH + lane;
    float r0 = b[0],   i0 = b[64],  j0 = b[128], k0 = b[192];
    float r1 = b[256], i1 = b[320], j1 = b[384], k1 = b[448];

    float ya0 = fmaf(m0, r0, fmaf(m1, i0, fmaf(m2, j0, fmaf(m3, k0, o0))));
    float ya1 = fmaf(m4, r0, fmaf(m5, i0, fmaf(m6, j0, fmaf(m7, k0, o1))));
    float ya2 = fmaf(m8, r0, fmaf(m9, i0, fmaf(m10,j0, fmaf(m11,k0, o2))));
    float ya3 = fmaf(m12,r0, fmaf(m13,i0, fmaf(m14,j0, fmaf(m15,k0, o3))));
    float yb0 = fmaf(m0, r1, fmaf(m1, i1, fmaf(m2, j1, fmaf(m3, k1, o0))));
    float yb1 = fmaf(m4, r1, fmaf(m5, i1, fmaf(m6, j1, fmaf(m7, k1, o1))));
    float yb2 = fmaf(m8, r1, fmaf(m9, i1, fmaf(m10,j1, fmaf(m11,k1, o2))));
    float yb3 = fmaf(m12,r1, fmaf(m13,i1, fmaf(m14,j1, fmaf(m15,k1, o3))));

    ya0 = ya0 > 0.f ? ya0 : (__expf(ya0) - 1.f);
    ya1 = ya1 > 0.f ? ya1 : (__expf(ya1) - 1.f);
    ya2 = ya2 > 0.f ? ya2 : (__expf(ya2) - 1.f);
    ya3 = ya3 > 0.f ? ya3 : (__expf(ya3) - 1.f);
    yb0 = yb0 > 0.f ? yb0 : (__expf(yb0) - 1.f);
    yb1 = yb1 > 0.f ? yb1 : (__expf(yb1) - 1.f);
    yb2 = yb2 > 0.f ? yb2 : (__expf(yb2) - 1.f);
    yb3 = yb3 > 0.f ? yb3 : (__expf(yb3) - 1.f);

    float* ob = out + (size_t)p * CCH + lane;
    __builtin_nontemporal_store(ya0, ob + 0);
    __builtin_nontemporal_store(ya1, ob + 64);
    __builtin_nontemporal_store(ya2, ob + 128);
    __builtin_nontemporal_store(ya3, ob + 192);
    __builtin_nontemporal_store(yb0, ob + 256);
    __builtin_nontemporal_store(yb1, ob + 320);
    __builtin_nontemporal_store(yb2, ob + 384);
    __builtin_nontemporal_store(yb3, ob + 448);
  }
}

extern "C" void kernel_launch(void* const* d_in, const int* in_sizes, int n_in,
                              void* d_out, int out_size, void* d_ws, size_t ws_size,
                              hipStream_t stream) {
  (void)in_sizes; (void)n_in; (void)out_size; (void)ws_size;
  const float* x    = (const float*)d_in[0];
  const float* beta = (const float*)d_in[1];
  const float* grr  = (const float*)d_in[2];
  const float* gri  = (const float*)d_in[3];
  const float* grj  = (const float*)d_in[4];
  const float* grk  = (const float*)d_in[5];
  const float* gii  = (const float*)d_in[6];
  const float* gij  = (const float*)d_in[7];
  const float* gik  = (const float*)d_in[8];
  const float* gjj  = (const float*)d_in[9];
  const float* gjk  = (const float*)d_in[10];
  const float* gkk  = (const float*)d_in[11];
  float* out = (float*)d_out;

  double* S   = (double*)d_ws;                                        // 14*64 f64 = 7168 B
  float* Mmat = (float*)((char*)d_ws + 14*64*sizeof(double));         // 64*16 f32
  float* offv = (float*)((char*)d_ws + 14*64*sizeof(double) + 64*16*sizeof(float)); // 256 f32

  // ws is NOT re-poisoned between replays: zero the accumulators every call.
  hipMemsetAsync(d_ws, 0, 14*64*sizeof(double), stream);
  hbn_reduce<<<2048, 256, 0, stream>>>(x, S);
  hbn_solve<<<1, 64, 0, stream>>>(S, beta, grr, gri, grj, grk,
                                  gii, gij, gik, gjj, gjk, gkk, Mmat, offv);
  hbn_apply<<<2048, 256, 0, stream>>>(x, Mmat, offv, out);
}

// Round 3
// 71.176 us; speedup vs baseline: 1.5394x; 1.5394x over previous
//
#include <hip/hip_runtime.h>
#include <math.h>

static constexpr int NPOS = 32 * 56 * 56;   // 100352 spatial positions
static constexpr int CCH  = 256;            // channels
static constexpr int NB   = 128;            // reduce blocks
static constexpr double EPSV = 1e-6;

// ws layout (bytes):
//   S      [896] f64      @ 0        (7168 B)
//   Mmat   [64*16] f32    @ 7168     (4096 B)
//   offv   [256] f32      @ 11264    (1024 B)
//   partial[NB][14][64]   @ 12288    (NB*896*4 = 458752 B)

// ---------------------------------------------------------------------------
// Kernel 1: per-d statistics, NO atomics. 128 blocks x 1024 threads
// (2048 waves). Lane = d. Each block LDS-reduces its 16 waves to 896 f32
// partials and writes them to its private slot.
// q=0..3 sums(r,i,j,k); q=4..13 products (rr,ri,rj,rk,ii,ij,ik,jj,jk,kk)
// ---------------------------------------------------------------------------
__global__ __launch_bounds__(1024) void hbn_reduce(const float* __restrict__ x,
                                                   float* __restrict__ partial) {
  const int tid  = threadIdx.x;
  const int lane = tid & 63;
  const int gw   = blockIdx.x * (blockDim.x >> 6) + (tid >> 6);
  const int nw   = NB * (1024 >> 6);           // 2048 waves

  float s0=0.f, s1=0.f, s2=0.f, s3=0.f;
  float q0=0.f,q1=0.f,q2=0.f,q3=0.f,q4=0.f,q5=0.f,q6=0.f,q7=0.f,q8=0.f,q9=0.f;

  for (int p = gw * 2; p < NPOS; p += nw * 2) {
    const float* b = x + (size_t)p * CCH + lane;
    float r0 = b[0],   i0 = b[64],  j0 = b[128], k0 = b[192];
    float r1 = b[256], i1 = b[320], j1 = b[384], k1 = b[448];
    s0 += r0 + r1; s1 += i0 + i1; s2 += j0 + j1; s3 += k0 + k1;
    q0 = fmaf(r0,r0, fmaf(r1,r1, q0));
    q1 = fmaf(r0,i0, fmaf(r1,i1, q1));
    q2 = fmaf(r0,j0, fmaf(r1,j1, q2));
    q3 = fmaf(r0,k0, fmaf(r1,k1, q3));
    q4 = fmaf(i0,i0, fmaf(i1,i1, q4));
    q5 = fmaf(i0,j0, fmaf(i1,j1, q5));
    q6 = fmaf(i0,k0, fmaf(i1,k1, q6));
    q7 = fmaf(j0,j0, fmaf(j1,j1, q7));
    q8 = fmaf(j0,k0, fmaf(j1,k1, q8));
    q9 = fmaf(k0,k0, fmaf(k1,k1, q9));
  }

  __shared__ float red[14][1024];
  red[0][tid]=s0;  red[1][tid]=s1;  red[2][tid]=s2;  red[3][tid]=s3;
  red[4][tid]=q0;  red[5][tid]=q1;  red[6][tid]=q2;  red[7][tid]=q3;
  red[8][tid]=q4;  red[9][tid]=q5;  red[10][tid]=q6; red[11][tid]=q7;
  red[12][tid]=q8; red[13][tid]=q9;
  __syncthreads();
  if (tid < 64) {
    float* dst = partial + (size_t)blockIdx.x * 896;
#pragma unroll
    for (int q = 0; q < 14; ++q) {
      float v = 0.f;
#pragma unroll
      for (int w = 0; w < 16; ++w) v += red[q][tid + 64*w];
      dst[q*64 + tid] = v;
    }
  }
}

// ---------------------------------------------------------------------------
// Kernel 2: sum partials over blocks (coalesced per-b rows), f64 accumulate.
// ---------------------------------------------------------------------------
__global__ __launch_bounds__(256) void hbn_sum(const float* __restrict__ partial,
                                               double* __restrict__ S) {
  const int t = blockIdx.x * 256 + threadIdx.x;
  if (t >= 896) return;
  double acc = 0.0;
#pragma unroll 8
  for (int b = 0; b < NB; ++b) acc += (double)partial[(size_t)b * 896 + t];
  S[t] = acc;
}

// ---------------------------------------------------------------------------
// Kernel 3: per-d 4x4 covariance (f64 assembly) -> V^{-1/2} via f32 Jacobi
// -> fold with affine G and mean/beta into M[d] (4x4) + per-channel offset.
// ---------------------------------------------------------------------------
__global__ void hbn_solve(const double* __restrict__ S,
                          const float* __restrict__ beta,
                          const float* __restrict__ grr, const float* __restrict__ gri,
                          const float* __restrict__ grj, const float* __restrict__ grk,
                          const float* __restrict__ gii, const float* __restrict__ gij,
                          const float* __restrict__ gik, const float* __restrict__ gjj,
                          const float* __restrict__ gjk, const float* __restrict__ gkk,
                          float* __restrict__ Mmat, float* __restrict__ offv) {
  const int d = threadIdx.x;   // 0..63
  const double invM = 1.0 / (double)NPOS;

  double mu[4];
  mu[0] = S[0*64+d]*invM; mu[1] = S[1*64+d]*invM;
  mu[2] = S[2*64+d]*invM; mu[3] = S[3*64+d]*invM;

  float A[4][4];
  A[0][0] = (float)(S[4*64+d]*invM  - mu[0]*mu[0] + EPSV);
  A[0][1] = A[1][0] = (float)(S[5*64+d]*invM  - mu[0]*mu[1]);
  A[0][2] = A[2][0] = (float)(S[6*64+d]*invM  - mu[0]*mu[2]);
  A[0][3] = A[3][0] = (float)(S[7*64+d]*invM  - mu[0]*mu[3]);
  A[1][1] = (float)(S[8*64+d]*invM  - mu[1]*mu[1] + EPSV);
  A[1][2] = A[2][1] = (float)(S[9*64+d]*invM  - mu[1]*mu[2]);
  A[1][3] = A[3][1] = (float)(S[10*64+d]*invM - mu[1]*mu[3]);
  A[2][2] = (float)(S[11*64+d]*invM - mu[2]*mu[2] + EPSV);
  A[2][3] = A[3][2] = (float)(S[12*64+d]*invM - mu[2]*mu[3]);
  A[3][3] = (float)(S[13*64+d]*invM - mu[3]*mu[3] + EPSV);

  float U[4][4] = {{1,0,0,0},{0,1,0,0},{0,0,1,0},{0,0,0,1}};

#pragma unroll 1
  for (int sweep = 0; sweep < 6; ++sweep) {
#pragma unroll
    for (int p = 0; p < 3; ++p) {
#pragma unroll
      for (int q = p + 1; q < 4; ++q) {
        float apq = A[p][q];
        if (fabsf(apq) > 1e-30f) {
          float theta = (A[q][q] - A[p][p]) / (2.0f * apq);
          float t = 1.0f / (fabsf(theta) + sqrtf(fmaf(theta, theta, 1.0f)));
          if (theta < 0.0f) t = -t;
          float c = rsqrtf(fmaf(t, t, 1.0f));
          float s = t * c;
#pragma unroll
          for (int r = 0; r < 4; ++r) {
            float arp = A[r][p], arq = A[r][q];
            A[r][p] = c*arp - s*arq;  A[r][q] = s*arp + c*arq;
          }
#pragma unroll
          for (int r = 0; r < 4; ++r) {
            float apr = A[p][r], aqr = A[q][r];
            A[p][r] = c*apr - s*aqr;  A[q][r] = s*apr + c*aqr;
          }
#pragma unroll
          for (int r = 0; r < 4; ++r) {
            float urp = U[r][p], urq = U[r][q];
            U[r][p] = c*urp - s*urq;  U[r][q] = s*urp + c*urq;
          }
        }
      }
    }
  }

  float wis[4];
#pragma unroll
  for (int b = 0; b < 4; ++b) {
    float w = A[b][b];
    if (w < 1e-12f) w = 1e-12f;
    wis[b] = rsqrtf(w);
  }

  float Wm[4][4];
#pragma unroll
  for (int a = 0; a < 4; ++a)
#pragma unroll
    for (int cc = 0; cc < 4; ++cc) {
      float acc = 0.0f;
#pragma unroll
      for (int b = 0; b < 4; ++b) acc += U[a][b] * wis[b] * U[cc][b];
      Wm[a][cc] = acc;
    }

  float G[4][4];
  G[0][0] = grr[d]; G[0][1] = G[1][0] = gri[d];
  G[0][2] = G[2][0] = grj[d]; G[0][3] = G[3][0] = grk[d];
  G[1][1] = gii[d]; G[1][2] = G[2][1] = gij[d];
  G[1][3] = G[3][1] = gik[d];
  G[2][2] = gjj[d]; G[2][3] = G[3][2] = gjk[d];
  G[3][3] = gkk[d];

  float M[4][4];
#pragma unroll
  for (int e = 0; e < 4; ++e)
#pragma unroll
    for (int cc = 0; cc < 4; ++cc) {
      float acc = 0.0f;
#pragma unroll
      for (int b = 0; b < 4; ++b) acc += G[e][b] * Wm[b][cc];
      M[e][cc] = acc;
      Mmat[d*16 + e*4 + cc] = acc;
    }

#pragma unroll
  for (int e = 0; e < 4; ++e) {
    float acc = beta[e*64 + d];
#pragma unroll
    for (int cc = 0; cc < 4; ++cc) acc -= M[e][cc] * (float)mu[cc];
    offv[e*64 + d] = acc;
  }
}

// ---------------------------------------------------------------------------
// Kernel 4: y = ELU(M[d] * x_rijk + off). Nontemporal stores (out never
// re-read; keeps x resident in L2/L3 for the reads).
// ---------------------------------------------------------------------------
__global__ __launch_bounds__(256) void hbn_apply(const float* __restrict__ x,
                                                 const float* __restrict__ Mmat,
                                                 const float* __restrict__ offv,
                                                 float* __restrict__ out) {
  const int tid  = threadIdx.x;
  const int lane = tid & 63;
  const int gw   = blockIdx.x * (blockDim.x >> 6) + (tid >> 6);
  const int nw   = gridDim.x * (blockDim.x >> 6);

  const float m0  = Mmat[lane*16+0],  m1  = Mmat[lane*16+1],  m2  = Mmat[lane*16+2],  m3  = Mmat[lane*16+3];
  const float m4  = Mmat[lane*16+4],  m5  = Mmat[lane*16+5],  m6  = Mmat[lane*16+6],  m7  = Mmat[lane*16+7];
  const float m8  = Mmat[lane*16+8],  m9  = Mmat[lane*16+9],  m10 = Mmat[lane*16+10], m11 = Mmat[lane*16+11];
  const float m12 = Mmat[lane*16+12], m13 = Mmat[lane*16+13], m14 = Mmat[lane*16+14], m15 = Mmat[lane*16+15];
  const float o0 = offv[lane], o1 = offv[64+lane], o2 = offv[128+lane], o3 = offv[192+lane];

  for (int p = gw * 2; p < NPOS; p += nw * 2) {
    const float* b = x + (size_t)p * CCH + lane;
    float r0 = b[0],   i0 = b[64],  j0 = b[128], k0 = b[192];
    float r1 = b[256], i1 = b[320], j1 = b[384], k1 = b[448];

    float ya0 = fmaf(m0, r0, fmaf(m1, i0, fmaf(m2, j0, fmaf(m3, k0, o0))));
    float ya1 = fmaf(m4, r0, fmaf(m5, i0, fmaf(m6, j0, fmaf(m7, k0, o1))));
    float ya2 = fmaf(m8, r0, fmaf(m9, i0, fmaf(m10,j0, fmaf(m11,k0, o2))));
    float ya3 = fmaf(m12,r0, fmaf(m13,i0, fmaf(m14,j0, fmaf(m15,k0, o3))));
    float yb0 = fmaf(m0, r1, fmaf(m1, i1, fmaf(m2, j1, fmaf(m3, k1, o0))));
    float yb1 = fmaf(m4, r1, fmaf(m5, i1, fmaf(m6, j1, fmaf(m7, k1, o1))));
    float yb2 = fmaf(m8, r1, fmaf(m9, i1, fmaf(m10,j1, fmaf(m11,k1, o2))));
    float yb3 = fmaf(m12,r1, fmaf(m13,i1, fmaf(m14,j1, fmaf(m15,k1, o3))));

    ya0 = ya0 > 0.f ? ya0 : (__expf(ya0) - 1.f);
    ya1 = ya1 > 0.f ? ya1 : (__expf(ya1) - 1.f);
    ya2 = ya2 > 0.f ? ya2 : (__expf(ya2) - 1.f);
    ya3 = ya3 > 0.f ? ya3 : (__expf(ya3) - 1.f);
    yb0 = yb0 > 0.f ? yb0 : (__expf(yb0) - 1.f);
    yb1 = yb1 > 0.f ? yb1 : (__expf(yb1) - 1.f);
    yb2 = yb2 > 0.f ? yb2 : (__expf(yb2) - 1.f);
    yb3 = yb3 > 0.f ? yb3 : (__expf(yb3) - 1.f);

    float* ob = out + (size_t)p * CCH + lane;
    __builtin_nontemporal_store(ya0, ob + 0);
    __builtin_nontemporal_store(ya1, ob + 64);
    __builtin_nontemporal_store(ya2, ob + 128);
    __builtin_nontemporal_store(ya3, ob + 192);
    __builtin_nontemporal_store(yb0, ob + 256);
    __builtin_nontemporal_store(yb1, ob + 320);
    __builtin_nontemporal_store(yb2, ob + 384);
    __builtin_nontemporal_store(yb3, ob + 448);
  }
}

extern "C" void kernel_launch(void* const* d_in, const int* in_sizes, int n_in,
                              void* d_out, int out_size, void* d_ws, size_t ws_size,
                              hipStream_t stream) {
  (void)in_sizes; (void)n_in; (void)out_size; (void)ws_size;
  const float* x    = (const float*)d_in[0];
  const float* beta = (const float*)d_in[1];
  const float* grr  = (const float*)d_in[2];
  const float* gri  = (const float*)d_in[3];
  const float* grj  = (const float*)d_in[4];
  const float* grk  = (const float*)d_in[5];
  const float* gii  = (const float*)d_in[6];
  const float* gij  = (const float*)d_in[7];
  const float* gik  = (const float*)d_in[8];
  const float* gjj  = (const float*)d_in[9];
  const float* gjk  = (const float*)d_in[10];
  const float* gkk  = (const float*)d_in[11];
  float* out = (float*)d_out;

  double* S      = (double*)d_ws;                         // 896 f64
  float*  Mmat   = (float*)((char*)d_ws + 7168);          // 1024 f32
  float*  offv   = (float*)((char*)d_ws + 11264);         // 256 f32
  float*  partial= (float*)((char*)d_ws + 12288);         // NB*896 f32

  hbn_reduce<<<NB, 1024, 0, stream>>>(x, partial);
  hbn_sum<<<4, 256, 0, stream>>>(partial, S);
  hbn_solve<<<1, 64, 0, stream>>>(S, beta, grr, gri, grj, grk,
                                  gii, gij, gik, gjj, gjk, gkk, Mmat, offv);
  hbn_apply<<<2048, 256, 0, stream>>>(x, Mmat, offv, out);
}